// Round 1
// baseline (119.954 us; speedup 1.0000x reference)
//
#include <hip/hip_runtime.h>

// loss = sum_{i} w[i] * sqrt( (0.5*kx+0.5 - rx)^2 + (0.5 - 0.5*ky - ry)^2 )
// z channel of kp3d is dead code in the reference (z_norm unused).
// Memory-bound streaming reduction: 96 MiB in, 4 B out.

__global__ void zero_out_kernel(float* out) {
    out[0] = 0.0f;
}

__global__ __launch_bounds__(256) void viewpoint_loss_kernel(
    const float* __restrict__ kp3d,   // B*N*3 floats, AoS (x,y,z)
    const float* __restrict__ ref,    // B*N*2 floats, AoS (rx,ry)
    const float* __restrict__ w,      // B*N floats
    float* __restrict__ out,
    int ngroups)                      // (B*N)/4
{
    const float4* kp4 = (const float4*)kp3d;
    const float4* rf4 = (const float4*)ref;
    const float4* w4  = (const float4*)w;

    float acc = 0.0f;
    int stride = gridDim.x * blockDim.x;
    for (int g = blockIdx.x * blockDim.x + threadIdx.x; g < ngroups; g += stride) {
        // 4 consecutive points per group: 12 kp3d floats, 8 ref floats, 4 weights
        float4 k0 = kp4[3 * g + 0];   // x0 y0 z0 x1
        float4 k1 = kp4[3 * g + 1];   // y1 z1 x2 y2
        float4 k2 = kp4[3 * g + 2];   // z2 x3 y3 z3
        float4 r0 = rf4[2 * g + 0];   // rx0 ry0 rx1 ry1
        float4 r1 = rf4[2 * g + 1];   // rx2 ry2 rx3 ry3
        float4 wv = w4[g];

        // x = 0.5*kx + 0.5 ; y = 0.5 - 0.5*ky
        float dx, dy;

        dx = fmaf(k0.x, 0.5f, 0.5f) - r0.x;
        dy = fmaf(k0.y, -0.5f, 0.5f) - r0.y;
        acc += wv.x * sqrtf(fmaf(dx, dx, dy * dy));

        dx = fmaf(k0.w, 0.5f, 0.5f) - r0.z;
        dy = fmaf(k1.x, -0.5f, 0.5f) - r0.w;
        acc += wv.y * sqrtf(fmaf(dx, dx, dy * dy));

        dx = fmaf(k1.z, 0.5f, 0.5f) - r1.x;
        dy = fmaf(k1.w, -0.5f, 0.5f) - r1.y;
        acc += wv.z * sqrtf(fmaf(dx, dx, dy * dy));

        dx = fmaf(k2.y, 0.5f, 0.5f) - r1.z;
        dy = fmaf(k2.z, -0.5f, 0.5f) - r1.w;
        acc += wv.w * sqrtf(fmaf(dx, dx, dy * dy));
    }

    // wave-64 reduction
    #pragma unroll
    for (int off = 32; off > 0; off >>= 1)
        acc += __shfl_down(acc, off, 64);

    __shared__ float wave_sums[4];  // 256 threads / 64
    int lane = threadIdx.x & 63;
    int wid  = threadIdx.x >> 6;
    if (lane == 0) wave_sums[wid] = acc;
    __syncthreads();

    if (threadIdx.x == 0) {
        float s = wave_sums[0] + wave_sums[1] + wave_sums[2] + wave_sums[3];
        atomicAdd(out, s);  // device-scope by default: safe across XCDs
    }
}

extern "C" void kernel_launch(void* const* d_in, const int* in_sizes, int n_in,
                              void* d_out, int out_size, void* d_ws, size_t ws_size,
                              hipStream_t stream) {
    const float* kp3d = (const float*)d_in[0];
    const float* ref  = (const float*)d_in[1];
    const float* w    = (const float*)d_in[2];
    float* out = (float*)d_out;

    int npts = in_sizes[2];        // B*N = 4194304
    int ngroups = npts / 4;        // exactly divisible (4096*1024)

    // d_out is poisoned to 0xAA before every timed call — must zero it.
    zero_out_kernel<<<1, 1, 0, stream>>>(out);

    // 1024 blocks x 256 threads = 262144 threads, 4 groups/thread.
    viewpoint_loss_kernel<<<1024, 256, 0, stream>>>(kp3d, ref, w, out, ngroups);
}

// Round 2
// 117.864 us; speedup vs baseline: 1.0177x; 1.0177x over previous
//
#include <hip/hip_runtime.h>

// loss = sum_i w[i] * sqrt( (0.5*kx+0.5 - rx)^2 + (0.5 - 0.5*ky - ry)^2 )
// z channel / z_norm in the reference is dead code (never feeds loss).
// Pure streaming reduction: 96 MiB read, 4 B written -> HBM-bound, ~16 us floor.
//
// Structure: main kernel writes one partial per block into d_ws (no atomics,
// no zero-init dependency), final 1-block kernel reduces partials and
// overwrites d_out (which is poisoned 0xAA before every call).

#define TPB 256

__global__ __launch_bounds__(TPB) void viewpoint_partial_kernel(
    const float* __restrict__ kp3d,   // B*N*3 floats, AoS (x,y,z)
    const float* __restrict__ ref,    // B*N*2 floats, AoS (rx,ry)
    const float* __restrict__ w,      // B*N floats
    float* __restrict__ partials,     // one float per block (d_ws)
    int T)                            // total threads; each handles groups tid, tid+T
{
    const float4* kp4 = (const float4*)kp3d;
    const float4* rf4 = (const float4*)ref;
    const float4* w4  = (const float4*)w;

    int tid = blockIdx.x * TPB + threadIdx.x;
    int g0 = tid;
    int g1 = tid + T;

    // Issue all 12 loads up front for max memory-level parallelism.
    float4 a0 = kp4[3 * g0 + 0];   // x0 y0 z0 x1
    float4 a1 = kp4[3 * g0 + 1];   // y1 z1 x2 y2
    float4 a2 = kp4[3 * g0 + 2];   // z2 x3 y3 z3
    float4 b0 = kp4[3 * g1 + 0];
    float4 b1 = kp4[3 * g1 + 1];
    float4 b2 = kp4[3 * g1 + 2];
    float4 r00 = rf4[2 * g0 + 0];  // rx0 ry0 rx1 ry1
    float4 r01 = rf4[2 * g0 + 1];  // rx2 ry2 rx3 ry3
    float4 r10 = rf4[2 * g1 + 0];
    float4 r11 = rf4[2 * g1 + 1];
    float4 w0 = w4[g0];
    float4 w1 = w4[g1];

    float acc = 0.0f;
    float dx, dy;

    // group 0: points 4*g0 .. 4*g0+3
    dx = fmaf(a0.x, 0.5f, 0.5f) - r00.x;
    dy = fmaf(a0.y, -0.5f, 0.5f) - r00.y;
    acc += w0.x * sqrtf(fmaf(dx, dx, dy * dy));

    dx = fmaf(a0.w, 0.5f, 0.5f) - r00.z;
    dy = fmaf(a1.x, -0.5f, 0.5f) - r00.w;
    acc += w0.y * sqrtf(fmaf(dx, dx, dy * dy));

    dx = fmaf(a1.z, 0.5f, 0.5f) - r01.x;
    dy = fmaf(a1.w, -0.5f, 0.5f) - r01.y;
    acc += w0.z * sqrtf(fmaf(dx, dx, dy * dy));

    dx = fmaf(a2.y, 0.5f, 0.5f) - r01.z;
    dy = fmaf(a2.z, -0.5f, 0.5f) - r01.w;
    acc += w0.w * sqrtf(fmaf(dx, dx, dy * dy));

    // group 1
    dx = fmaf(b0.x, 0.5f, 0.5f) - r10.x;
    dy = fmaf(b0.y, -0.5f, 0.5f) - r10.y;
    acc += w1.x * sqrtf(fmaf(dx, dx, dy * dy));

    dx = fmaf(b0.w, 0.5f, 0.5f) - r10.z;
    dy = fmaf(b1.x, -0.5f, 0.5f) - r10.w;
    acc += w1.y * sqrtf(fmaf(dx, dx, dy * dy));

    dx = fmaf(b1.z, 0.5f, 0.5f) - r11.x;
    dy = fmaf(b1.w, -0.5f, 0.5f) - r11.y;
    acc += w1.z * sqrtf(fmaf(dx, dx, dy * dy));

    dx = fmaf(b2.y, 0.5f, 0.5f) - r11.z;
    dy = fmaf(b2.z, -0.5f, 0.5f) - r11.w;
    acc += w1.w * sqrtf(fmaf(dx, dx, dy * dy));

    // wave-64 butterfly reduction
    #pragma unroll
    for (int off = 32; off > 0; off >>= 1)
        acc += __shfl_down(acc, off, 64);

    __shared__ float wave_sums[TPB / 64];
    int lane = threadIdx.x & 63;
    int wid  = threadIdx.x >> 6;
    if (lane == 0) wave_sums[wid] = acc;
    __syncthreads();

    if (threadIdx.x == 0) {
        partials[blockIdx.x] = wave_sums[0] + wave_sums[1]
                             + wave_sums[2] + wave_sums[3];
    }
}

__global__ __launch_bounds__(256) void final_reduce_kernel(
    const float* __restrict__ partials, float* __restrict__ out, int n)
{
    float acc = 0.0f;
    for (int i = threadIdx.x; i < n; i += 256)
        acc += partials[i];

    #pragma unroll
    for (int off = 32; off > 0; off >>= 1)
        acc += __shfl_down(acc, off, 64);

    __shared__ float wave_sums[4];
    int lane = threadIdx.x & 63;
    int wid  = threadIdx.x >> 6;
    if (lane == 0) wave_sums[wid] = acc;
    __syncthreads();

    if (threadIdx.x == 0)
        out[0] = wave_sums[0] + wave_sums[1] + wave_sums[2] + wave_sums[3];
}

extern "C" void kernel_launch(void* const* d_in, const int* in_sizes, int n_in,
                              void* d_out, int out_size, void* d_ws, size_t ws_size,
                              hipStream_t stream) {
    const float* kp3d = (const float*)d_in[0];
    const float* ref  = (const float*)d_in[1];
    const float* w    = (const float*)d_in[2];
    float* out = (float*)d_out;
    float* partials = (float*)d_ws;

    int npts = in_sizes[2];        // B*N = 4194304
    int ngroups = npts / 4;        // 1048576 (exactly divisible)
    int T = ngroups / 2;           // 524288 threads, 2 groups each
    int blocks = T / TPB;          // 2048

    viewpoint_partial_kernel<<<blocks, TPB, 0, stream>>>(kp3d, ref, w, partials, T);
    final_reduce_kernel<<<1, 256, 0, stream>>>(partials, out, blocks);
}